// Round 18
// baseline (61.329 us; speedup 1.0000x reference)
//
#include <hip/hip_runtime.h>
#include <math.h>

#define LN_EPS 1e-5f

// Problem constants (fixed by setup_inputs): N=10, K=5, Q=5, H=256, Qtot=50
constexpr int Nn  = 10;
constexpr int Kk  = 5;
constexpr int Hh  = 256;
constexpr int QT  = 50;
constexpr int QH  = 25;   // QT/2: queries per group in C/F
constexpr int NP1 = 11;

// ---------- DPP-based reductions (VALU pipe; zero DS-pipe ops) ----------
template<int CTRL, int RM>
__device__ __forceinline__ float dpp_term(float x) {
    return __int_as_float(__builtin_amdgcn_update_dpp(
        0, __float_as_int(x), CTRL, RM, 0xf, true));   // bound_ctrl: OOB -> 0
}
// broadcast sum across each 16-lane group (4 DPP adds)
__device__ __forceinline__ float sum16_bcast(float v) {
    v += dpp_term<0xB1,  0xf>(v);   // quad_perm [1,0,3,2]
    v += dpp_term<0x4E,  0xf>(v);   // quad_perm [2,3,0,1]
    v += dpp_term<0x124, 0xf>(v);   // row_ror:4
    v += dpp_term<0x128, 0xf>(v);   // row_ror:8 -> full 16-sum, all lanes
    return v;
}
// wave sum accumulated into lane 63 (6 DPP adds)
__device__ __forceinline__ float sum64_lane63(float v) {
    v += dpp_term<0x111, 0xf>(v);   // row_shr:1
    v += dpp_term<0x112, 0xf>(v);   // row_shr:2
    v += dpp_term<0x114, 0xf>(v);   // row_shr:4
    v += dpp_term<0x118, 0xf>(v);   // row_shr:8
    v += dpp_term<0x142, 0xa>(v);   // row_bcast:15 -> rows 1,3
    v += dpp_term<0x143, 0xc>(v);   // row_bcast:31 -> rows 2,3 (lane63 = total)
    return v;
}
__device__ __forceinline__ float rdlane(float v, int l) {
    return __int_as_float(__builtin_amdgcn_readlane(__float_as_int(v), l));
}
__device__ __forceinline__ float wave64_sum_bcast(float v) {
    return rdlane(sum64_lane63(v), 63);
}

// One batch per 1024-thread block (16 waves). 3 barriers.
// __launch_bounds__(1024, 2): 2nd arg = min BLOCKS/CU (CUDA semantics).
// (1024,8) clamped VGPR to 32 for rounds 3-16; (1024,2) = the real occupancy
// -> 64-VGPR budget (verified r17: VGPR_Count=64).
// Dual-query C/F in n-OUTER form (live ~55 <= 64): ya16+yb16 = 32 regs, M
// fragments transient per-n. sched_barrier(0) per n-iter stops the scheduler
// from clustering all 40 M-loads (the r15/r17 ~70-reg transient spill).
// A  (waves 0-9):  support stream: LN inline (sstat->LDS), M->MP_s, ||M||^2,
//                  support scores.
// A' (waves 10-15): query stream (2-deep pipeline): LN'd y -> qy_s, ny -> ny_s.
// C  (groups 0-24, TWO queries q,q+25): each M row read ONCE per n, used for
//                  both dots -> C/F LDS-pipe instruction count halved
//                  (the ~11us > 8.3us HBM-floor binding term per r16 analysis).
//                  argmin(nM-2p), wq/cq/counts.  B (groups 56-60): softmax.
// E  (waves 0-9):  rectified prototype; ballot loop reads qy_s; proto->MP_s.
// F  (groups 0-24, dual query): d=ny+np-2p, logits+pred.
// LDS ~63KB/block -> 2 blocks/CU. NOTE: nothing register-live across barriers.
__global__ __launch_bounds__(1024, 2) void proto_rectify_fused(
    const float* __restrict__ support, const float* __restrict__ query,
    const float* __restrict__ gamma,   const float* __restrict__ beta,
    float* __restrict__ out, int B)
{
    const int b    = blockIdx.x;
    const int tid  = threadIdx.x;
    const int lane = tid & 63;
    const int wave = tid >> 6;   // 0..15
    const int grp  = tid >> 4;   // 0..63
    const int sub  = tid & 15;

    __shared__ float qy_s[QT][Hh];        // LN'd query rows (51.2 KB)
    __shared__ float MP_s[Nn][Hh];        // M (A-C), then proto (E-F)
    __shared__ float nM_s[Nn], np_s[Nn];
    __shared__ float ny_s[QT];
    __shared__ float score_s[Nn * Kk];
    __shared__ float wsup_s[Nn * Kk];
    __shared__ float wq_s[QT];
    __shared__ int   cq_s[QT];
    __shared__ float sstat_s[Nn * Kk][2]; // support row: mu, rstd
    __shared__ int   cnt_s[Nn];

    const float* supB = support + (size_t)b * (Nn * Kk * Hh);
    const float* qryB = query   + (size_t)b * (QT * Hh);

    if (tid < Nn) cnt_s[tid] = 0;

    // ---------------- Phase A / A' ----------------
    const float4 g4 = *reinterpret_cast<const float4*>(gamma + lane * 4);  // L1
    const float4 b4 = *reinterpret_cast<const float4*>(beta  + lane * 4);
    if (wave < Nn) {
        const int n = wave;
        const float* rows = supB + (size_t)n * Kk * Hh;

        float y[Kk][4];
#pragma unroll
        for (int k = 0; k < Kk; ++k) {
            const float4 x = *reinterpret_cast<const float4*>(rows + k * Hh + lane * 4);
            float s  = x.x + x.y + x.z + x.w;
            float ss = x.x * x.x + x.y * x.y + x.z * x.z + x.w * x.w;
            s  = wave64_sum_bcast(s);
            ss = wave64_sum_bcast(ss);
            const float mu   = s * (1.0f / (float)Hh);
            const float rstd = rsqrtf(ss * (1.0f / (float)Hh) - mu * mu + LN_EPS);
            if (lane == 0) { sstat_s[n * Kk + k][0] = mu; sstat_s[n * Kk + k][1] = rstd; }
            y[k][0] = (x.x - mu) * rstd * g4.x + b4.x;
            y[k][1] = (x.y - mu) * rstd * g4.y + b4.y;
            y[k][2] = (x.z - mu) * rstd * g4.z + b4.z;
            y[k][3] = (x.w - mu) * rstd * g4.w + b4.w;
        }
        float Mv[4];
#pragma unroll
        for (int i = 0; i < 4; ++i)
            Mv[i] = (y[0][i] + y[1][i] + y[2][i] + y[3][i] + y[4][i]) / 5.0f;
        *reinterpret_cast<float4*>(&MP_s[n][lane * 4]) =
            make_float4(Mv[0], Mv[1], Mv[2], Mv[3]);

        float pm = Mv[0] * Mv[0];
        pm = fmaf(Mv[1], Mv[1], pm); pm = fmaf(Mv[2], Mv[2], pm); pm = fmaf(Mv[3], Mv[3], pm);
        pm = sum64_lane63(pm);
        if (lane == 63) nM_s[n] = pm;

#pragma unroll
        for (int k = 0; k < Kk; ++k) {
            float p = y[k][0] * Mv[0];
            p = fmaf(y[k][1], Mv[1], p); p = fmaf(y[k][2], Mv[2], p); p = fmaf(y[k][3], Mv[3], p);
            p = sum64_lane63(p);
            if (lane == 63) score_s[n * Kk + k] = p;
        }
    } else {
        // A': waves 10-15 stream + LN query rows into qy_s (2-deep pipeline)
        int r = wave - 10;
        float4 x = make_float4(0.f, 0.f, 0.f, 0.f);
        if (r < QT) x = *reinterpret_cast<const float4*>(qryB + (size_t)r * Hh + lane * 4);
        while (r < QT) {
            const int rn = r + 6;
            float4 xn = x;
            if (rn < QT)                       // issue next load before chains
                xn = *reinterpret_cast<const float4*>(qryB + (size_t)rn * Hh + lane * 4);
            float s  = x.x + x.y + x.z + x.w;
            float ss = fmaf(x.x, x.x, fmaf(x.y, x.y, fmaf(x.z, x.z, x.w * x.w)));
            s  = wave64_sum_bcast(s);
            ss = wave64_sum_bcast(ss);
            const float mu   = s * (1.0f / (float)Hh);
            const float rstd = rsqrtf(ss * (1.0f / (float)Hh) - mu * mu + LN_EPS);
            const float y0 = (x.x - mu) * rstd * g4.x + b4.x;
            const float y1 = (x.y - mu) * rstd * g4.y + b4.y;
            const float y2 = (x.z - mu) * rstd * g4.z + b4.z;
            const float y3 = (x.w - mu) * rstd * g4.w + b4.w;
            *reinterpret_cast<float4*>(&qy_s[r][lane * 4]) =
                make_float4(y0, y1, y2, y3);
            float ny = fmaf(y0, y0, fmaf(y1, y1, fmaf(y2, y2, y3 * y3)));
            ny = sum64_lane63(ny);
            if (lane == 63) ny_s[r] = ny;
            x = xn; r = rn;
        }
    }
    __syncthreads();

    // ---------------- C (groups 0-24, dual query, n-outer) + B ----------------
    if (grp < QH) {
        const int q0 = grp, q1 = grp + QH;
        const float nmv = (lane < Nn) ? nM_s[lane] : 0.f;   // hoist ||M||^2
        float ya[16], yb[16];
#pragma unroll
        for (int c = 0; c < 4; ++c) {
            const float4 va = *reinterpret_cast<const float4*>(&qy_s[q0][c * 64 + sub * 4]);
            ya[c * 4 + 0] = va.x; ya[c * 4 + 1] = va.y;
            ya[c * 4 + 2] = va.z; ya[c * 4 + 3] = va.w;
            const float4 vb = *reinterpret_cast<const float4*>(&qy_s[q1][c * 64 + sub * 4]);
            yb[c * 4 + 0] = vb.x; yb[c * 4 + 1] = vb.y;
            yb[c * 4 + 2] = vb.z; yb[c * 4 + 3] = vb.w;
        }
        float bestdA = INFINITY, bestdotA = 0.f; int bestnA = 0;
        float bestdB = INFINITY, bestdotB = 0.f; int bestnB = 0;
#pragma unroll
        for (int n = 0; n < Nn; ++n) {
            __builtin_amdgcn_sched_barrier(0);   // cap transient regs: no cross-n load hoist
            float pa, pb;
            {
                const float4 m = *reinterpret_cast<const float4*>(&MP_s[n][0 * 64 + sub * 4]);
                pa = ya[0] * m.x;            pb = yb[0] * m.x;
                pa = fmaf(ya[1], m.y, pa);   pb = fmaf(yb[1], m.y, pb);
                pa = fmaf(ya[2], m.z, pa);   pb = fmaf(yb[2], m.z, pb);
                pa = fmaf(ya[3], m.w, pa);   pb = fmaf(yb[3], m.w, pb);
            }
            {
                const float4 m = *reinterpret_cast<const float4*>(&MP_s[n][1 * 64 + sub * 4]);
                pa = fmaf(ya[4], m.x, pa);   pb = fmaf(yb[4], m.x, pb);
                pa = fmaf(ya[5], m.y, pa);   pb = fmaf(yb[5], m.y, pb);
                pa = fmaf(ya[6], m.z, pa);   pb = fmaf(yb[6], m.z, pb);
                pa = fmaf(ya[7], m.w, pa);   pb = fmaf(yb[7], m.w, pb);
            }
            {
                const float4 m = *reinterpret_cast<const float4*>(&MP_s[n][2 * 64 + sub * 4]);
                pa = fmaf(ya[8],  m.x, pa);  pb = fmaf(yb[8],  m.x, pb);
                pa = fmaf(ya[9],  m.y, pa);  pb = fmaf(yb[9],  m.y, pb);
                pa = fmaf(ya[10], m.z, pa);  pb = fmaf(yb[10], m.z, pb);
                pa = fmaf(ya[11], m.w, pa);  pb = fmaf(yb[11], m.w, pb);
            }
            {
                const float4 m = *reinterpret_cast<const float4*>(&MP_s[n][3 * 64 + sub * 4]);
                pa = fmaf(ya[12], m.x, pa);  pb = fmaf(yb[12], m.x, pb);
                pa = fmaf(ya[13], m.y, pa);  pb = fmaf(yb[13], m.y, pb);
                pa = fmaf(ya[14], m.z, pa);  pb = fmaf(yb[14], m.z, pb);
                pa = fmaf(ya[15], m.w, pa);  pb = fmaf(yb[15], m.w, pb);
            }
            pa = sum16_bcast(pa);
            pb = sum16_bcast(pb);
            const float nm = rdlane(nmv, n);
            const float da = nm - 2.0f * pa;   // argmin drops ny (const per q)
            const float db = nm - 2.0f * pb;
            if (da < bestdA) { bestdA = da; bestnA = n; bestdotA = pa; }
            if (db < bestdB) { bestdB = db; bestnB = n; bestdotB = pb; }
        }
        if (sub == 0) {
            {
                const float mx  = fmaxf(bestdotA, 0.f);
                const float e   = expf(bestdotA - mx);
                const float den = e + (float)(Nn - 1) * expf(-mx);
                wq_s[q0] = e / den;  cq_s[q0] = bestnA;
                atomicAdd(&cnt_s[bestnA], 1);
            }
            {
                const float mx  = fmaxf(bestdotB, 0.f);
                const float e   = expf(bestdotB - mx);
                const float den = e + (float)(Nn - 1) * expf(-mx);
                wq_s[q1] = e / den;  cq_s[q1] = bestnB;
                atomicAdd(&cnt_s[bestnB], 1);
            }
        }
    } else if (grp >= 56 && grp < 56 + Kk && sub == 0) {
        const int k = grp - 56;
        float mx = -INFINITY;
#pragma unroll
        for (int n = 0; n < Nn; ++n) mx = fmaxf(mx, score_s[n * Kk + k]);
        float e[Nn]; float den = 0.f;
#pragma unroll
        for (int n = 0; n < Nn; ++n) { e[n] = expf(score_s[n * Kk + k] - mx); den += e[n]; }
#pragma unroll
        for (int n = 0; n < Nn; ++n) wsup_s[n * Kk + k] = e[n] / den;
    }
    __syncthreads();

    // ---------------- E (waves 0-9): rectified prototype -> MP_s -------------
    if (wave < Nn) {
        const int n = wave;
        const float* rows = supB + (size_t)n * Kk * Hh;

        float acc[4] = {0.f, 0.f, 0.f, 0.f};
#pragma unroll
        for (int k = 0; k < Kk; ++k) {
            const float w    = wsup_s[n * Kk + k];
            const float mu   = sstat_s[n * Kk + k][0];
            const float rstd = sstat_s[n * Kk + k][1];
            const float4 x = *reinterpret_cast<const float4*>(rows + k * Hh + lane * 4);
            acc[0] = fmaf(w, (x.x - mu) * rstd * g4.x + b4.x, acc[0]);
            acc[1] = fmaf(w, (x.y - mu) * rstd * g4.y + b4.y, acc[1]);
            acc[2] = fmaf(w, (x.z - mu) * rstd * g4.z + b4.z, acc[2]);
            acc[3] = fmaf(w, (x.w - mu) * rstd * g4.w + b4.w, acc[3]);
        }
        // ballot-compressed query rectification; LN'd y read from qy_s (LDS)
        int myc = -1; float myw = 0.f;
        if (lane < QT) { myc = cq_s[lane]; myw = wq_s[lane]; }
        unsigned long long mask = __ballot(lane < QT && myc == n);
        while (mask) {
            const int q = __ffsll(mask) - 1;
            mask &= mask - 1;
            const float w = rdlane(myw, q);
            const float4 yv = *reinterpret_cast<const float4*>(&qy_s[q][lane * 4]);
            acc[0] = fmaf(w, yv.x, acc[0]);
            acc[1] = fmaf(w, yv.y, acc[1]);
            acc[2] = fmaf(w, yv.z, acc[2]);
            acc[3] = fmaf(w, yv.w, acc[3]);
        }
        const float inv = 1.0f / (float)(Kk + cnt_s[n]);
        float pv[4];
#pragma unroll
        for (int i = 0; i < 4; ++i) pv[i] = acc[i] * inv;
        *reinterpret_cast<float4*>(&MP_s[n][lane * 4]) =      // proto overwrites M
            make_float4(pv[0], pv[1], pv[2], pv[3]);
        float pp = pv[0] * pv[0];
        pp = fmaf(pv[1], pv[1], pp); pp = fmaf(pv[2], pv[2], pp); pp = fmaf(pv[3], pv[3], pp);
        pp = sum64_lane63(pp);
        if (lane == 63) np_s[n] = pp;
    }
    __syncthreads();

    // ---------------- F (groups 0-24, dual query, n-outer): logits + pred ----
    if (grp < QH) {
        const int q0 = grp, q1 = grp + QH;
        const float npv = (lane < Nn) ? np_s[lane] : 0.f;    // hoist ||p||^2
        float ya[16], yb[16];
#pragma unroll
        for (int c = 0; c < 4; ++c) {
            const float4 va = *reinterpret_cast<const float4*>(&qy_s[q0][c * 64 + sub * 4]);
            ya[c * 4 + 0] = va.x; ya[c * 4 + 1] = va.y;
            ya[c * 4 + 2] = va.z; ya[c * 4 + 3] = va.w;
            const float4 vb = *reinterpret_cast<const float4*>(&qy_s[q1][c * 64 + sub * 4]);
            yb[c * 4 + 0] = vb.x; yb[c * 4 + 1] = vb.y;
            yb[c * 4 + 2] = vb.z; yb[c * 4 + 3] = vb.w;
        }
        const float nya = ny_s[q0], nyb = ny_s[q1];

        float mineA = 0.f, maxdA = -INFINITY, bestdA = INFINITY; int bestnA = 0;
        float mineB = 0.f, maxdB = -INFINITY, bestdB = INFINITY; int bestnB = 0;
#pragma unroll
        for (int n = 0; n < Nn; ++n) {
            __builtin_amdgcn_sched_barrier(0);   // cap transient regs
            float pa, pb;
            {
                const float4 m = *reinterpret_cast<const float4*>(&MP_s[n][0 * 64 + sub * 4]);
                pa = ya[0] * m.x;            pb = yb[0] * m.x;
                pa = fmaf(ya[1], m.y, pa);   pb = fmaf(yb[1], m.y, pb);
                pa = fmaf(ya[2], m.z, pa);   pb = fmaf(yb[2], m.z, pb);
                pa = fmaf(ya[3], m.w, pa);   pb = fmaf(yb[3], m.w, pb);
            }
            {
                const float4 m = *reinterpret_cast<const float4*>(&MP_s[n][1 * 64 + sub * 4]);
                pa = fmaf(ya[4], m.x, pa);   pb = fmaf(yb[4], m.x, pb);
                pa = fmaf(ya[5], m.y, pa);   pb = fmaf(yb[5], m.y, pb);
                pa = fmaf(ya[6], m.z, pa);   pb = fmaf(yb[6], m.z, pb);
                pa = fmaf(ya[7], m.w, pa);   pb = fmaf(yb[7], m.w, pb);
            }
            {
                const float4 m = *reinterpret_cast<const float4*>(&MP_s[n][2 * 64 + sub * 4]);
                pa = fmaf(ya[8],  m.x, pa);  pb = fmaf(yb[8],  m.x, pb);
                pa = fmaf(ya[9],  m.y, pa);  pb = fmaf(yb[9],  m.y, pb);
                pa = fmaf(ya[10], m.z, pa);  pb = fmaf(yb[10], m.z, pb);
                pa = fmaf(ya[11], m.w, pa);  pb = fmaf(yb[11], m.w, pb);
            }
            {
                const float4 m = *reinterpret_cast<const float4*>(&MP_s[n][3 * 64 + sub * 4]);
                pa = fmaf(ya[12], m.x, pa);  pb = fmaf(yb[12], m.x, pb);
                pa = fmaf(ya[13], m.y, pa);  pb = fmaf(yb[13], m.y, pb);
                pa = fmaf(ya[14], m.z, pa);  pb = fmaf(yb[14], m.z, pb);
                pa = fmaf(ya[15], m.w, pa);  pb = fmaf(yb[15], m.w, pb);
            }
            pa = sum16_bcast(pa);
            pb = sum16_bcast(pb);
            const float np = rdlane(npv, n);
            const float da = nya + np - 2.0f * pa;
            const float db = nyb + np - 2.0f * pb;
            if (sub == n) { mineA = da; mineB = db; }   // cndmask, d group-uniform
            maxdA = fmaxf(maxdA, da);
            maxdB = fmaxf(maxdB, db);
            if (da < bestdA) { bestdA = da; bestnA = n; }
            if (db < bestdB) { bestdB = db; bestnB = n; }
        }
        if (sub == Nn) { mineA = -maxdA - 1.0f; mineB = -maxdB - 1.0f; }
        else           { mineA = -mineA;        mineB = -mineB; }
        float* o0 = out + ((size_t)b * QT + q0) * NP1;
        float* o1 = out + ((size_t)b * QT + q1) * NP1;
        if (sub <= Nn) { o0[sub] = mineA; o1[sub] = mineB; }
        if (sub == Nn + 1) {
            out[(size_t)B * QT * NP1 + (size_t)b * QT + q0] = (float)bestnA;
            out[(size_t)B * QT * NP1 + (size_t)b * QT + q1] = (float)bestnB;
        }
    }
}

extern "C" void kernel_launch(void* const* d_in, const int* in_sizes, int n_in,
                              void* d_out, int out_size, void* d_ws, size_t ws_size,
                              hipStream_t stream) {
    const float* support = (const float*)d_in[0];
    const float* query   = (const float*)d_in[1];
    const float* gamma   = (const float*)d_in[2];
    const float* beta    = (const float*)d_in[3];
    float* out = (float*)d_out;

    const int B = in_sizes[0] / (Nn * Kk * Hh);   // 512
    proto_rectify_fused<<<B, 1024, 0, stream>>>(support, query, gamma, beta, out, B);
}

// Round 19
// 24.722 us; speedup vs baseline: 2.4808x; 2.4808x over previous
//
#include <hip/hip_runtime.h>
#include <math.h>

#define LN_EPS 1e-5f

// Problem constants (fixed by setup_inputs): N=10, K=5, Q=5, H=256, Qtot=50
constexpr int Nn  = 10;
constexpr int Kk  = 5;
constexpr int Hh  = 256;
constexpr int QT  = 50;
constexpr int NP1 = 11;

// ---------- DPP-based reductions (VALU pipe; zero DS-pipe ops) ----------
template<int CTRL, int RM>
__device__ __forceinline__ float dpp_term(float x) {
    return __int_as_float(__builtin_amdgcn_update_dpp(
        0, __float_as_int(x), CTRL, RM, 0xf, true));   // bound_ctrl: OOB -> 0
}
// broadcast sum across each 16-lane group (4 DPP adds)
__device__ __forceinline__ float sum16_bcast(float v) {
    v += dpp_term<0xB1,  0xf>(v);   // quad_perm [1,0,3,2]
    v += dpp_term<0x4E,  0xf>(v);   // quad_perm [2,3,0,1]
    v += dpp_term<0x124, 0xf>(v);   // row_ror:4
    v += dpp_term<0x128, 0xf>(v);   // row_ror:8 -> full 16-sum, all lanes
    return v;
}
// wave sum accumulated into lane 63 (6 DPP adds)
__device__ __forceinline__ float sum64_lane63(float v) {
    v += dpp_term<0x111, 0xf>(v);   // row_shr:1
    v += dpp_term<0x112, 0xf>(v);   // row_shr:2
    v += dpp_term<0x114, 0xf>(v);   // row_shr:4
    v += dpp_term<0x118, 0xf>(v);   // row_shr:8
    v += dpp_term<0x142, 0xa>(v);   // row_bcast:15 -> rows 1,3
    v += dpp_term<0x143, 0xc>(v);   // row_bcast:31 -> rows 2,3 (lane63 = total)
    return v;
}
__device__ __forceinline__ float rdlane(float v, int l) {
    return __int_as_float(__builtin_amdgcn_readlane(__float_as_int(v), l));
}
__device__ __forceinline__ float wave64_sum_bcast(float v) {
    return rdlane(sum64_lane63(v), 63);
}

// 16-lane-group dot of y16 vs an LDS row, ILP-4 (4 independent chains + tree)
__device__ __forceinline__ float dot16_ilp4(const float y16[16],
                                            const float* __restrict__ rowbase,
                                            int sub) {
    float p0, p1, p2, p3;
    {
        const float4 v = *reinterpret_cast<const float4*>(rowbase + 0 * 64 + sub * 4);
        p0 = y16[0] * v.x; p0 = fmaf(y16[1], v.y, p0);
        p0 = fmaf(y16[2], v.z, p0); p0 = fmaf(y16[3], v.w, p0);
    }
    {
        const float4 v = *reinterpret_cast<const float4*>(rowbase + 1 * 64 + sub * 4);
        p1 = y16[4] * v.x; p1 = fmaf(y16[5], v.y, p1);
        p1 = fmaf(y16[6], v.z, p1); p1 = fmaf(y16[7], v.w, p1);
    }
    {
        const float4 v = *reinterpret_cast<const float4*>(rowbase + 2 * 64 + sub * 4);
        p2 = y16[8] * v.x; p2 = fmaf(y16[9], v.y, p2);
        p2 = fmaf(y16[10], v.z, p2); p2 = fmaf(y16[11], v.w, p2);
    }
    {
        const float4 v = *reinterpret_cast<const float4*>(rowbase + 3 * 64 + sub * 4);
        p3 = y16[12] * v.x; p3 = fmaf(y16[13], v.y, p3);
        p3 = fmaf(y16[14], v.z, p3); p3 = fmaf(y16[15], v.w, p3);
    }
    return (p0 + p1) + (p2 + p3);
}

// One batch per 1024-thread block (16 waves). 3 barriers.
// ROUND-16 PROVEN STRUCTURE (24.9us) + two fixes:
//  1. __launch_bounds__(1024, 2): 2nd arg = min BLOCKS/CU (CUDA semantics).
//     (1024,8) had clamped VGPR to 32 since round 3; 2 = real occupancy ->
//     64-VGPR budget, allocator slack for the ~30-live single-query body.
//     (Dual-query C/F needs ~70 live -> spilled 4x; abandoned.)
//  2. ny moved A' -> C (4 ILP partials + sum16 on already-loaded y16):
//     A' drops to 2 chains/row, balancing phase-A wave workloads (~17 vs 16).
// A  (waves 0-9):  support stream: LN inline (sstat->LDS), M->MP_s, ||M||^2,
//                  support scores.
// A' (waves 10-15): query stream, 2-deep pipeline: LN'd y -> qy_s.
// C  (groups 0-49): y16 from qy_s, ny->LDS, dots vs M (ILP-4 + sum16),
//                  argmin(nM-2p), wq/cq/counts.  B (groups 56-60): softmax.
// E  (waves 0-9):  rectified prototype; ballot loop reads qy_s; proto->MP_s.
// F  (groups 0-49): y16 from qy_s, dots vs proto, d=ny+np-2p, logits+pred.
// LDS ~63KB/block -> 2 blocks/CU. NOTE: nothing register-live across barriers.
__global__ __launch_bounds__(1024, 2) void proto_rectify_fused(
    const float* __restrict__ support, const float* __restrict__ query,
    const float* __restrict__ gamma,   const float* __restrict__ beta,
    float* __restrict__ out, int B)
{
    const int b    = blockIdx.x;
    const int tid  = threadIdx.x;
    const int lane = tid & 63;
    const int wave = tid >> 6;   // 0..15
    const int grp  = tid >> 4;   // 0..63
    const int sub  = tid & 15;

    __shared__ float qy_s[QT][Hh];        // LN'd query rows (51.2 KB)
    __shared__ float MP_s[Nn][Hh];        // M (A-C), then proto (E-F)
    __shared__ float nM_s[Nn], np_s[Nn];
    __shared__ float ny_s[QT];
    __shared__ float score_s[Nn * Kk];
    __shared__ float wsup_s[Nn * Kk];
    __shared__ float wq_s[QT];
    __shared__ int   cq_s[QT];
    __shared__ float sstat_s[Nn * Kk][2]; // support row: mu, rstd
    __shared__ int   cnt_s[Nn];

    const float* supB = support + (size_t)b * (Nn * Kk * Hh);
    const float* qryB = query   + (size_t)b * (QT * Hh);

    if (tid < Nn) cnt_s[tid] = 0;

    // ---------------- Phase A / A' ----------------
    const float4 g4 = *reinterpret_cast<const float4*>(gamma + lane * 4);  // L1
    const float4 b4 = *reinterpret_cast<const float4*>(beta  + lane * 4);
    if (wave < Nn) {
        const int n = wave;
        const float* rows = supB + (size_t)n * Kk * Hh;

        float y[Kk][4];
#pragma unroll
        for (int k = 0; k < Kk; ++k) {
            const float4 x = *reinterpret_cast<const float4*>(rows + k * Hh + lane * 4);
            float s  = x.x + x.y + x.z + x.w;
            float ss = x.x * x.x + x.y * x.y + x.z * x.z + x.w * x.w;
            s  = wave64_sum_bcast(s);
            ss = wave64_sum_bcast(ss);
            const float mu   = s * (1.0f / (float)Hh);
            const float rstd = rsqrtf(ss * (1.0f / (float)Hh) - mu * mu + LN_EPS);
            if (lane == 0) { sstat_s[n * Kk + k][0] = mu; sstat_s[n * Kk + k][1] = rstd; }
            y[k][0] = (x.x - mu) * rstd * g4.x + b4.x;
            y[k][1] = (x.y - mu) * rstd * g4.y + b4.y;
            y[k][2] = (x.z - mu) * rstd * g4.z + b4.z;
            y[k][3] = (x.w - mu) * rstd * g4.w + b4.w;
        }
        float Mv[4];
#pragma unroll
        for (int i = 0; i < 4; ++i)
            Mv[i] = (y[0][i] + y[1][i] + y[2][i] + y[3][i] + y[4][i]) / 5.0f;
        *reinterpret_cast<float4*>(&MP_s[n][lane * 4]) =
            make_float4(Mv[0], Mv[1], Mv[2], Mv[3]);

        float pm = Mv[0] * Mv[0];
        pm = fmaf(Mv[1], Mv[1], pm); pm = fmaf(Mv[2], Mv[2], pm); pm = fmaf(Mv[3], Mv[3], pm);
        pm = sum64_lane63(pm);
        if (lane == 63) nM_s[n] = pm;

#pragma unroll
        for (int k = 0; k < Kk; ++k) {
            float p = y[k][0] * Mv[0];
            p = fmaf(y[k][1], Mv[1], p); p = fmaf(y[k][2], Mv[2], p); p = fmaf(y[k][3], Mv[3], p);
            p = sum64_lane63(p);
            if (lane == 63) score_s[n * Kk + k] = p;
        }
    } else {
        // A': waves 10-15 stream + LN query rows into qy_s (2-deep pipeline).
        // ny computed in C from y16 (A' down to 2 chains/row -> balanced with A).
        int r = wave - 10;
        float4 x = make_float4(0.f, 0.f, 0.f, 0.f);
        if (r < QT) x = *reinterpret_cast<const float4*>(qryB + (size_t)r * Hh + lane * 4);
        while (r < QT) {
            const int rn = r + 6;
            float4 xn = x;
            if (rn < QT)                       // issue next load before chains
                xn = *reinterpret_cast<const float4*>(qryB + (size_t)rn * Hh + lane * 4);
            float s  = x.x + x.y + x.z + x.w;
            float ss = fmaf(x.x, x.x, fmaf(x.y, x.y, fmaf(x.z, x.z, x.w * x.w)));
            s  = wave64_sum_bcast(s);
            ss = wave64_sum_bcast(ss);
            const float mu   = s * (1.0f / (float)Hh);
            const float rstd = rsqrtf(ss * (1.0f / (float)Hh) - mu * mu + LN_EPS);
            *reinterpret_cast<float4*>(&qy_s[r][lane * 4]) = make_float4(
                (x.x - mu) * rstd * g4.x + b4.x,
                (x.y - mu) * rstd * g4.y + b4.y,
                (x.z - mu) * rstd * g4.z + b4.z,
                (x.w - mu) * rstd * g4.w + b4.w);
            x = xn; r = rn;
        }
    }
    __syncthreads();

    // ---------------- C (groups 0-49) + B (groups 56-60) ----------------
    if (grp < QT) {
        const int q = grp;
        const float nmv = (lane < Nn) ? nM_s[lane] : 0.f;   // hoist ||M||^2
        float y16[16];
#pragma unroll
        for (int c = 0; c < 4; ++c) {
            const float4 v = *reinterpret_cast<const float4*>(&qy_s[q][c * 64 + sub * 4]);
            y16[c * 4 + 0] = v.x; y16[c * 4 + 1] = v.y;
            y16[c * 4 + 2] = v.z; y16[c * 4 + 3] = v.w;
        }
        // ny: 4 ILP partial chains + one sum16 (moved from A')
        {
            float n0 = fmaf(y16[0], y16[0], fmaf(y16[1], y16[1],
                       fmaf(y16[2], y16[2], y16[3] * y16[3])));
            float n1 = fmaf(y16[4], y16[4], fmaf(y16[5], y16[5],
                       fmaf(y16[6], y16[6], y16[7] * y16[7])));
            float n2 = fmaf(y16[8], y16[8], fmaf(y16[9], y16[9],
                       fmaf(y16[10], y16[10], y16[11] * y16[11])));
            float n3 = fmaf(y16[12], y16[12], fmaf(y16[13], y16[13],
                       fmaf(y16[14], y16[14], y16[15] * y16[15])));
            const float ny = sum16_bcast((n0 + n1) + (n2 + n3));
            if (sub == 0) ny_s[q] = ny;
        }
        float bestd = INFINITY, bestdot = 0.f;
        int bestn = 0;
#pragma unroll
        for (int n = 0; n < Nn; ++n) {
            float p = dot16_ilp4(y16, &MP_s[n][0], sub);
            p = sum16_bcast(p);
            const float d = rdlane(nmv, n) - 2.0f * p;   // argmin drops ny (const/q)
            if (d < bestd) { bestd = d; bestn = n; bestdot = p; }  // first-min tie-break
        }
        if (sub == 0) {
            const float sc  = bestdot;             // <q, M_bestn>
            const float mx  = fmaxf(sc, 0.f);
            const float e   = expf(sc - mx);
            const float den = e + (float)(Nn - 1) * expf(-mx);
            wq_s[q] = e / den;
            cq_s[q] = bestn;
            atomicAdd(&cnt_s[bestn], 1);
        }
    } else if (grp >= 56 && grp < 56 + Kk && sub == 0) {
        const int k = grp - 56;
        float mx = -INFINITY;
#pragma unroll
        for (int n = 0; n < Nn; ++n) mx = fmaxf(mx, score_s[n * Kk + k]);
        float e[Nn]; float den = 0.f;
#pragma unroll
        for (int n = 0; n < Nn; ++n) { e[n] = expf(score_s[n * Kk + k] - mx); den += e[n]; }
#pragma unroll
        for (int n = 0; n < Nn; ++n) wsup_s[n * Kk + k] = e[n] / den;
    }
    __syncthreads();

    // ---------------- E (waves 0-9): rectified prototype -> MP_s ----------------
    if (wave < Nn) {
        const int n = wave;
        const float* rows = supB + (size_t)n * Kk * Hh;

        float acc[4] = {0.f, 0.f, 0.f, 0.f};
#pragma unroll
        for (int k = 0; k < Kk; ++k) {
            const float w    = wsup_s[n * Kk + k];
            const float mu   = sstat_s[n * Kk + k][0];
            const float rstd = sstat_s[n * Kk + k][1];
            const float4 x = *reinterpret_cast<const float4*>(rows + k * Hh + lane * 4);
            acc[0] = fmaf(w, (x.x - mu) * rstd * g4.x + b4.x, acc[0]);
            acc[1] = fmaf(w, (x.y - mu) * rstd * g4.y + b4.y, acc[1]);
            acc[2] = fmaf(w, (x.z - mu) * rstd * g4.z + b4.z, acc[2]);
            acc[3] = fmaf(w, (x.w - mu) * rstd * g4.w + b4.w, acc[3]);
        }
        // ballot-compressed query rectification; LN'd y read from qy_s (LDS)
        int myc = -1; float myw = 0.f;
        if (lane < QT) { myc = cq_s[lane]; myw = wq_s[lane]; }
        unsigned long long mask = __ballot(lane < QT && myc == n);
        while (mask) {
            const int q = __ffsll(mask) - 1;
            mask &= mask - 1;
            const float w = rdlane(myw, q);
            const float4 yv = *reinterpret_cast<const float4*>(&qy_s[q][lane * 4]);
            acc[0] = fmaf(w, yv.x, acc[0]);
            acc[1] = fmaf(w, yv.y, acc[1]);
            acc[2] = fmaf(w, yv.z, acc[2]);
            acc[3] = fmaf(w, yv.w, acc[3]);
        }
        const float inv = 1.0f / (float)(Kk + cnt_s[n]);
        float pv[4];
#pragma unroll
        for (int i = 0; i < 4; ++i) pv[i] = acc[i] * inv;
        *reinterpret_cast<float4*>(&MP_s[n][lane * 4]) =      // proto overwrites M
            make_float4(pv[0], pv[1], pv[2], pv[3]);
        float pp = pv[0] * pv[0];
        pp = fmaf(pv[1], pv[1], pp); pp = fmaf(pv[2], pv[2], pp); pp = fmaf(pv[3], pv[3], pp);
        pp = sum64_lane63(pp);
        if (lane == 63) np_s[n] = pp;
    }
    __syncthreads();

    // ---------------- F (groups 0-49): logits + pred ----------------
    if (grp < QT) {
        const int q = grp;
        const float npv = (lane < Nn) ? np_s[lane] : 0.f;    // hoist ||p||^2
        float y16[16];
#pragma unroll
        for (int c = 0; c < 4; ++c) {
            const float4 v = *reinterpret_cast<const float4*>(&qy_s[q][c * 64 + sub * 4]);
            y16[c * 4 + 0] = v.x; y16[c * 4 + 1] = v.y;
            y16[c * 4 + 2] = v.z; y16[c * 4 + 3] = v.w;
        }
        const float ny = ny_s[q];

        float mine = 0.f, maxd = -INFINITY, bestd = INFINITY;
        int bestn = 0;
#pragma unroll
        for (int n = 0; n < Nn; ++n) {
            float p = dot16_ilp4(y16, &MP_s[n][0], sub);     // proto
            p = sum16_bcast(p);
            const float d = ny + rdlane(npv, n) - 2.0f * p;
            if (sub == n) mine = d;
            maxd = fmaxf(maxd, d);
            if (d < bestd) { bestd = d; bestn = n; }
        }
        float* o = out + ((size_t)b * QT + q) * NP1;
        if (sub < Nn)       o[sub] = -mine;
        else if (sub == Nn) o[Nn]  = -maxd - 1.0f;           // min(logits) - 1
        else if (sub == Nn + 1)
            out[(size_t)B * QT * NP1 + (size_t)b * QT + q] = (float)bestn;
    }
}

extern "C" void kernel_launch(void* const* d_in, const int* in_sizes, int n_in,
                              void* d_out, int out_size, void* d_ws, size_t ws_size,
                              hipStream_t stream) {
    const float* support = (const float*)d_in[0];
    const float* query   = (const float*)d_in[1];
    const float* gamma   = (const float*)d_in[2];
    const float* beta    = (const float*)d_in[3];
    float* out = (float*)d_out;

    const int B = in_sizes[0] / (Nn * Kk * Hh);   // 512
    proto_rectify_fused<<<B, 1024, 0, stream>>>(support, query, gamma, beta, out, B);
}